// Round 11
// baseline (253.663 us; speedup 1.0000x reference)
//
#include <hip/hip_runtime.h>

#define NBATCH 32
#define CHAN   512
#define HWSZ   4096
#define NG     8
#define NM     64
#define MTOT   (NBATCH * HWSZ)   // 131072 samples per channel
#define EPSC   0.01f
#define P68    68                // padded LDS row stride for solve matrices

typedef _Float16 f16;
typedef _Float16 f16x8 __attribute__((ext_vector_type(8)));
typedef float    f32x4 __attribute__((ext_vector_type(4)));

#define MFMA16(a, b, c) __builtin_amdgcn_mfma_f32_16x16x32_f16(a, b, c, 0, 0, 0)

// ---------------------------------------------------------------------------
// Kernel 1: per-block partial Gram via f16 MFMA, STAGING DOUBLE-BUFFERED:
// issue tile t+1 global loads into registers before tile t's MFMA phase,
// LDS-write after, one barrier per tile -> ~2x bytes in flight per CU.
// LDS tile swizzle off8 ^= (ch&7)<<3 (validated R5); A-frag == B-frag.
// ---------------------------------------------------------------------------
__global__ __launch_bounds__(256) void gram_k(const float* __restrict__ x,
                                              float* __restrict__ gpart,
                                              float* __restrict__ spart) {
    __shared__ __align__(16) f16 tile[2][64 * 128];   // 32KB
    __shared__ float red[2][4096];                    // 32KB

    const int bid  = blockIdx.x;     // 0..511
    const int g    = bid >> 6;
    const int n    = (bid >> 1) & 31;
    const int half = bid & 1;
    const float* xb = x + ((size_t)(n * CHAN + g * NM)) * HWSZ + half * 2048;

    const int t = threadIdx.x;
    const int w = t >> 6;            // wave 0..3
    const int l = t & 63;

    const int chS   = t >> 4;        // staging: +16 per i
    const int off8S = (t & 15) * 8;

    f32x4 acc[4][4];
#pragma unroll
    for (int i = 0; i < 4; ++i)
#pragma unroll
        for (int j = 0; j < 4; ++j) acc[i][j] = (f32x4){0.f, 0.f, 0.f, 0.f};
    float fsum[4] = {0.f, 0.f, 0.f, 0.f};

    // ---- prologue: stage tile 0 into buffer 0 ----
#pragma unroll
    for (int i = 0; i < 4; ++i) {
        const int ch = chS + 16 * i;
        const float4 v0 = *(const float4*)(xb + (size_t)ch * HWSZ + off8S);
        const float4 v1 = *(const float4*)(xb + (size_t)ch * HWSZ + off8S + 4);
        fsum[i] += (v0.x + v0.y) + (v0.z + v0.w) + (v1.x + v1.y) + (v1.z + v1.w);
        f16x8 hv;
        hv[0] = (f16)v0.x; hv[1] = (f16)v0.y; hv[2] = (f16)v0.z; hv[3] = (f16)v0.w;
        hv[4] = (f16)v1.x; hv[5] = (f16)v1.y; hv[6] = (f16)v1.z; hv[7] = (f16)v1.w;
        *(f16x8*)&tile[0][ch * 128 + (off8S ^ ((ch & 7) << 3))] = hv;
    }
    __syncthreads();

    for (int tt = 0; tt < 16; ++tt) {
        // ---- issue next tile's loads early ----
        float4 va[4][2];
        if (tt < 15) {
            const float* xt = xb + (tt + 1) * 128;
#pragma unroll
            for (int i = 0; i < 4; ++i) {
                const int ch = chS + 16 * i;
                va[i][0] = *(const float4*)(xt + (size_t)ch * HWSZ + off8S);
                va[i][1] = *(const float4*)(xt + (size_t)ch * HWSZ + off8S + 4);
            }
        }

        // ---- fragments + MFMA on current buffer ----
        const f16* tb = tile[tt & 1];
        f16x8 frag[4];
#pragma unroll
        for (int rb = 0; rb < 4; ++rb) {
            const int ch = rb * 16 + (l & 15);
            const int k0 = w * 32 + (l >> 4) * 8;
            frag[rb] = *(const f16x8*)&tb[ch * 128 + (k0 ^ ((ch & 7) << 3))];
        }
#pragma unroll
        for (int i = 0; i < 4; ++i)
#pragma unroll
            for (int j = 0; j < 4; ++j)
                acc[i][j] = MFMA16(frag[i], frag[j], acc[i][j]);

        // ---- cvt + write staged registers into the other buffer ----
        if (tt < 15) {
            f16* tn = tile[(tt + 1) & 1];
#pragma unroll
            for (int i = 0; i < 4; ++i) {
                const int ch = chS + 16 * i;
                const float4 v0 = va[i][0], v1 = va[i][1];
                fsum[i] += (v0.x + v0.y) + (v0.z + v0.w) + (v1.x + v1.y) + (v1.z + v1.w);
                f16x8 hv;
                hv[0] = (f16)v0.x; hv[1] = (f16)v0.y; hv[2] = (f16)v0.z; hv[3] = (f16)v0.w;
                hv[4] = (f16)v1.x; hv[5] = (f16)v1.y; hv[6] = (f16)v1.z; hv[7] = (f16)v1.w;
                *(f16x8*)&tn[ch * 128 + (off8S ^ ((ch & 7) << 3))] = hv;
            }
        }
        __syncthreads();
    }

    // ---- per-channel sums: staging layout -> reduce 16 pos-lanes ----
#pragma unroll
    for (int i = 0; i < 4; ++i) {
        fsum[i] += __shfl_xor(fsum[i], 1);
        fsum[i] += __shfl_xor(fsum[i], 2);
        fsum[i] += __shfl_xor(fsum[i], 4);
        fsum[i] += __shfl_xor(fsum[i], 8);
    }
    if ((l & 15) == 0) {
        const int chb = t >> 4;
#pragma unroll
        for (int i = 0; i < 4; ++i)
            spart[(size_t)bid * 64 + chb + 16 * i] = fsum[i];
    }

    // ---- cross-wave accumulator reduce in 2 stages ----
    if (w >= 2) {
#pragma unroll
        for (int i = 0; i < 4; ++i)
#pragma unroll
            for (int j = 0; j < 4; ++j)
#pragma unroll
                for (int r = 0; r < 4; ++r) {
                    const int row = i * 16 + (l >> 4) * 4 + r;
                    const int col = j * 16 + (l & 15);
                    red[w - 2][row * 64 + col] = acc[i][j][r];
                }
    }
    __syncthreads();
    if (w < 2) {
#pragma unroll
        for (int i = 0; i < 4; ++i)
#pragma unroll
            for (int j = 0; j < 4; ++j)
#pragma unroll
                for (int r = 0; r < 4; ++r) {
                    const int row = i * 16 + (l >> 4) * 4 + r;
                    const int col = j * 16 + (l & 15);
                    red[w][row * 64 + col] += acc[i][j][r];
                }
    }
    __syncthreads();
#pragma unroll
    for (int k = 0; k < 16; ++k) {
        const int e = t + 256 * k;
        gpart[(size_t)bid * 4096 + e] = red[0][e] + red[1][e];
    }
}

// ---------------------------------------------------------------------------
// Kernel 2: per-group inverse matrix sqrt (validated R10): fused partial
// reduction + [5/5] Pade + Neumann-4 solve P^{-1}Q (||E||~0.06 -> 8e-7 rel).
// ---------------------------------------------------------------------------
__global__ __launch_bounds__(256) void solve_k(const float* __restrict__ gpart,
                                               const float* __restrict__ spart,
                                               const float* __restrict__ wgt,
                                               const float* __restrict__ bias,
                                               f16* __restrict__ Tf,
                                               float* __restrict__ offv) {
    __shared__ __align__(16) float A[64 * P68];
    __shared__ __align__(16) float B[64 * P68];
    __shared__ __align__(16) float Cc[64 * P68];
    __shared__ __align__(16) float Dd[64 * P68];
    __shared__ float mus[64];
    __shared__ float red[4];
    __shared__ float tr16[16];

    const int g = blockIdx.x, t = threadIdx.x;

    float covv[16], cov2[16];
#pragma unroll
    for (int k = 0; k < 16; ++k) { covv[k] = 0.f; cov2[k] = 0.f; }
    for (int p = 0; p < 64; p += 2) {
        const float* gp0 = gpart + ((size_t)(g * 64 + p)) * 4096;
        const float* gp1 = gp0 + 4096;
#pragma unroll
        for (int k = 0; k < 16; ++k) {
            covv[k] += gp0[t + 256 * k];
            cov2[k] += gp1[t + 256 * k];
        }
    }
#pragma unroll
    for (int k = 0; k < 16; ++k) covv[k] += cov2[k];

    if (t < 64) {
        float ss = 0.f;
#pragma unroll 8
        for (int p = 0; p < 64; ++p) ss += spart[(size_t)(g * 64 + p) * 64 + t];
        mus[t] = ss * (1.0f / MTOT);
    }
    __syncthreads();

    float loc = 0.f;
#pragma unroll
    for (int k = 0; k < 16; ++k) {
        const int e = t + 256 * k;
        const int i = e >> 6, j = e & 63;
        const float cv = covv[k] * (1.0f / MTOT) - mus[i] * mus[j] + (i == j ? EPSC : 0.f);
        covv[k] = cv;
        loc += cv * cv;
    }
#pragma unroll
    for (int o = 32; o > 0; o >>= 1) loc += __shfl_down(loc, o);
    if ((t & 63) == 0) red[t >> 6] = loc;
    __syncthreads();
    const float normM = sqrtf(red[0] + red[1] + red[2] + red[3]);
    const float ninv  = 1.0f / normM;

#pragma unroll
    for (int k = 0; k < 16; ++k) {
        const int e = t + 256 * k;
        const int i = e >> 6, j = e & 63;
        const float pa = (i == j ? 1.f : 0.f) - covv[k] * ninv;
        A[i * P68 + j] = pa;
        B[i * P68 + j] = pa;
    }
    __syncthreads();

    const int ty = t >> 4, tx = t & 15;
    const int i0 = ty * 4, j0 = tx * 4;

    const float PP[6] = {1.f, -2.75f, 2.75f, -1.203125f, 0.21484375f, -0.0107421875f};
    const float QQ[6] = {1.f, -2.25f, 1.75f, -0.546875f, 0.05859375f, -0.0009765625f};

    float pacc[4][4], qacc[4][4];
#pragma unroll
    for (int ai = 0; ai < 4; ++ai)
#pragma unroll
        for (int bi = 0; bi < 4; ++bi) {
            const int i = i0 + ai, j = j0 + bi;
            const float pa = A[i * P68 + j];
            const float id = (i == j) ? 1.f : 0.f;
            pacc[ai][bi] = PP[0] * id + PP[1] * pa;
            qacc[ai][bi] = QQ[0] * id + QQ[1] * pa;
        }

    float* src = B;
    float* dst = Cc;
    for (int s = 0; s < 4; ++s) {
        float mm[4][4];
#pragma unroll
        for (int ai = 0; ai < 4; ++ai)
#pragma unroll
            for (int bi = 0; bi < 4; ++bi) mm[ai][bi] = 0.f;
        for (int kk = 0; kk < 64; ++kk) {
            const float4 a4 = *(const float4*)&src[kk * P68 + i0];
            const float4 b4 = *(const float4*)&A[kk * P68 + j0];
            const float av[4] = {a4.x, a4.y, a4.z, a4.w};
            const float bv[4] = {b4.x, b4.y, b4.z, b4.w};
#pragma unroll
            for (int ai = 0; ai < 4; ++ai)
#pragma unroll
                for (int bi = 0; bi < 4; ++bi)
                    mm[ai][bi] = fmaf(av[ai], bv[bi], mm[ai][bi]);
        }
#pragma unroll
        for (int ai = 0; ai < 4; ++ai) {
            float4 w4;
            w4.x = mm[ai][0]; w4.y = mm[ai][1]; w4.z = mm[ai][2]; w4.w = mm[ai][3];
            *(float4*)&dst[(i0 + ai) * P68 + j0] = w4;
        }
#pragma unroll
        for (int ai = 0; ai < 4; ++ai)
#pragma unroll
            for (int bi = 0; bi < 4; ++bi) {
                pacc[ai][bi] = fmaf(PP[s + 2], mm[ai][bi], pacc[ai][bi]);
                qacc[ai][bi] = fmaf(QQ[s + 2], mm[ai][bi], qacc[ai][bi]);
            }
        __syncthreads();
        float* tmpp = src; src = dst; dst = tmpp;
    }

    if (ty == tx)
        tr16[tx] = pacc[0][0] + pacc[1][1] + pacc[2][2] + pacc[3][3];
    __syncthreads();
    float trsum = 0.f;
#pragma unroll
    for (int i = 0; i < 16; ++i) trsum += tr16[i];
    const float cP  = trsum * (1.0f / 64.0f);
    const float icP = 1.0f / cP;

#pragma unroll
    for (int ai = 0; ai < 4; ++ai) {
        float4 we, wq;
        const int i = i0 + ai;
        we.x = pacc[ai][0] * icP - (i == j0 + 0 ? 1.f : 0.f);
        we.y = pacc[ai][1] * icP - (i == j0 + 1 ? 1.f : 0.f);
        we.z = pacc[ai][2] * icP - (i == j0 + 2 ? 1.f : 0.f);
        we.w = pacc[ai][3] * icP - (i == j0 + 3 ? 1.f : 0.f);
        wq.x = qacc[ai][0]; wq.y = qacc[ai][1]; wq.z = qacc[ai][2]; wq.w = qacc[ai][3];
        *(float4*)&A[i * P68 + j0] = we;
        *(float4*)&B[i * P68 + j0] = wq;
    }
    __syncthreads();

    float* rsrc = B;
    float* rdst = Cc;
    for (int it = 0; it < 4; ++it) {
        float mm[4][4];
#pragma unroll
        for (int ai = 0; ai < 4; ++ai)
#pragma unroll
            for (int bi = 0; bi < 4; ++bi) mm[ai][bi] = 0.f;
        for (int kk = 0; kk < 64; ++kk) {
            const float4 a4 = *(const float4*)&A[kk * P68 + i0];
            const float4 b4 = *(const float4*)&rsrc[kk * P68 + j0];
            const float av[4] = {a4.x, a4.y, a4.z, a4.w};
            const float bv[4] = {b4.x, b4.y, b4.z, b4.w};
#pragma unroll
            for (int ai = 0; ai < 4; ++ai)
#pragma unroll
                for (int bi = 0; bi < 4; ++bi)
                    mm[ai][bi] = fmaf(av[ai], bv[bi], mm[ai][bi]);
        }
#pragma unroll
        for (int ai = 0; ai < 4; ++ai) {
            const float4 q4 = *(const float4*)&B[(i0 + ai) * P68 + j0];
            float4 w4;
            w4.x = q4.x - mm[ai][0]; w4.y = q4.y - mm[ai][1];
            w4.z = q4.z - mm[ai][2]; w4.w = q4.w - mm[ai][3];
            *(float4*)&rdst[(i0 + ai) * P68 + j0] = w4;
        }
        __syncthreads();
        if (it == 0) { rsrc = Cc; rdst = Dd; }
        else { float* tmpp = rsrc; rsrc = rdst; rdst = tmpp; }
    }
    float* X = rsrc;

    const float invs = icP / sqrtf(normM);
    if (t < 64) {
        float sm = 0.f;
        for (int j = 0; j < 64; ++j) sm += X[t * P68 + j] * mus[j];
        offv[g * NM + t] = bias[g * NM + t] - sm * invs * wgt[g * NM + t];
    }
#pragma unroll
    for (int k = 0; k < 16; ++k) {
        const int e = t + 256 * k;
        const int i = e >> 6, j = e & 63;
        Tf[(size_t)g * 4096 + e] = (f16)(X[i * P68 + j] * invs * wgt[g * NM + i]);
    }
}

// ---------------------------------------------------------------------------
// Kernel 3: out = T @ x + off via f16 MFMA (R5-validated 2-barrier staging),
// grid 1024 (4 blocks/CU, 16 waves/CU) with REVERSED block order for L3
// reuse of gram's freshest x slices.
// ---------------------------------------------------------------------------
__global__ __launch_bounds__(256) void apply_k(const float* __restrict__ x,
                                               const f16* __restrict__ Tf,
                                               const float* __restrict__ offv,
                                               float* __restrict__ out) {
    __shared__ __align__(16) f16 xs[128 * 64];
    __shared__ __align__(16) f16 Ts[4096];
    __shared__ float offs[64];

    const int bid  = 1023 - (int)blockIdx.x;  // reverse: freshest slices first
    const int g    = bid >> 7;
    const int rest = bid & 127;
    const int n    = rest >> 2;
    const int q    = rest & 3;
    const size_t base = ((size_t)(n * CHAN + g * NM)) * HWSZ + q * 1024;
    const float* xb = x + base;
    float* ob = out + base;

    const int t = threadIdx.x;
    const int w = t >> 6;
    const int l = t & 63;

#pragma unroll
    for (int i = 0; i < 2; ++i) {
        const int c   = t + 256 * i;
        const int oc  = c >> 3;
        const int icb = (c & 7) * 8;
        const f16x8 v = *(const f16x8*)&Tf[(size_t)g * 4096 + oc * 64 + icb];
        *(f16x8*)&Ts[oc * 64 + (icb ^ ((oc & 7) << 3))] = v;
    }
    if (t < 64) offs[t] = offv[g * NM + t];
    __syncthreads();

    f16x8 afrag[2];
#pragma unroll
    for (int c = 0; c < 2; ++c) {
        const int oc = w * 16 + (l & 15);
        const int k0 = c * 32 + (l >> 4) * 8;
        afrag[c] = *(const f16x8*)&Ts[oc * 64 + (k0 ^ ((oc & 7) << 3))];
    }
    float offr[4];
#pragma unroll
    for (int r = 0; r < 4; ++r) offr[r] = offs[w * 16 + (l >> 4) * 4 + r];

    for (int tt = 0; tt < 8; ++tt) {
        const float* xt = xb + tt * 128;
        __syncthreads();
#pragma unroll
        for (int i = 0; i < 4; ++i) {
            const int p    = t + 256 * i;
            const int ch   = p >> 4;
            const int off8 = (p & 15) * 8;
            const float4 v0 = *(const float4*)(xt + (size_t)ch * HWSZ + off8);
            const float4 v1 = *(const float4*)(xt + (size_t)ch * HWSZ + off8 + 4);
            f16 h[8];
            h[0] = (f16)v0.x; h[1] = (f16)v0.y; h[2] = (f16)v0.z; h[3] = (f16)v0.w;
            h[4] = (f16)v1.x; h[5] = (f16)v1.y; h[6] = (f16)v1.z; h[7] = (f16)v1.w;
#pragma unroll
            for (int j = 0; j < 8; ++j) {
                const int pos = off8 + j;
                xs[pos * 64 + (ch ^ (((pos ^ (pos >> 3)) & 7) << 3))] = h[j];
            }
        }
        __syncthreads();

#pragma unroll
        for (int pb = 0; pb < 8; ++pb) {
            f32x4 acc;
            acc[0] = offr[0]; acc[1] = offr[1]; acc[2] = offr[2]; acc[3] = offr[3];
            const int pos = pb * 16 + (l & 15);
            const int swz = ((pos ^ (pos >> 3)) & 7) << 3;
#pragma unroll
            for (int c = 0; c < 2; ++c) {
                const int k0 = c * 32 + (l >> 4) * 8;
                const f16x8 bfrag = *(const f16x8*)&xs[pos * 64 + (k0 ^ swz)];
                acc = MFMA16(afrag[c], bfrag, acc);
            }
            const int posg = tt * 128 + pb * 16 + (l & 15);
#pragma unroll
            for (int r = 0; r < 4; ++r) {
                const int oc = w * 16 + (l >> 4) * 4 + r;
                ob[(size_t)oc * HWSZ + posg] = acc[r];
            }
        }
    }
}

// ---------------------------------------------------------------------------
extern "C" void kernel_launch(void* const* d_in, const int* in_sizes, int n_in,
                              void* d_out, int out_size, void* d_ws, size_t ws_size,
                              hipStream_t stream) {
    const float* x    = (const float*)d_in[0];
    const float* wgt  = (const float*)d_in[1];
    const float* bias = (const float*)d_in[2];
    float* out = (float*)d_out;

    float* ws    = (float*)d_ws;
    float* gpart = ws;                        // 512*4096 floats (8MB)
    float* spart = ws + 2097152;              // 512*64
    float* offv  = ws + 2129920;              // 512
    f16*   Tf    = (f16*)(ws + 2130432);      // 8*4096 halves

    gram_k <<<512,  256, 0, stream>>>(x, gpart, spart);
    solve_k<<<8,    256, 0, stream>>>(gpart, spart, wgt, bias, Tf, offv);
    apply_k<<<1024, 256, 0, stream>>>(x, Tf, offv, out);
}

// Round 12
// 215.162 us; speedup vs baseline: 1.1789x; 1.1789x over previous
//
#include <hip/hip_runtime.h>

#define NBATCH 32
#define CHAN   512
#define HWSZ   4096
#define NG     8
#define NM     64
#define MTOT   (NBATCH * HWSZ)   // 131072 samples per channel
#define EPSC   0.01f
#define P68    68                // padded LDS row stride for solve matrices

typedef _Float16 f16;
typedef _Float16 f16x8 __attribute__((ext_vector_type(8)));
typedef float    f32x4 __attribute__((ext_vector_type(4)));

#define MFMA16(a, b, c) __builtin_amdgcn_mfma_f32_16x16x32_f16(a, b, c, 0, 0, 0)

// ---------------------------------------------------------------------------
// Kernel 1: per-block partial Gram via f16 MFMA + per-channel partial sums.
// R5/R10-validated LDS-staged version. LDS tile [64 ch][128 pos] f16,
// swizzle off8 ^= (ch&7)<<3; A-frag == B-frag for X X^T.
// ---------------------------------------------------------------------------
__global__ __launch_bounds__(256) void gram_k(const float* __restrict__ x,
                                              float* __restrict__ gpart,
                                              float* __restrict__ spart) {
    __shared__ __align__(16) f16 tile[64 * 128];
    __shared__ float red[2][4096];

    const int bid  = blockIdx.x;     // 0..511
    const int g    = bid >> 6;
    const int n    = (bid >> 1) & 31;
    const int half = bid & 1;
    const float* xb = x + ((size_t)(n * CHAN + g * NM)) * HWSZ + half * 2048;

    const int t = threadIdx.x;
    const int w = t >> 6;            // wave 0..3
    const int l = t & 63;

    f32x4 acc[4][4];
#pragma unroll
    for (int i = 0; i < 4; ++i)
#pragma unroll
        for (int j = 0; j < 4; ++j) acc[i][j] = (f32x4){0.f, 0.f, 0.f, 0.f};
    float fsum[4] = {0.f, 0.f, 0.f, 0.f};

    for (int tt = 0; tt < 16; ++tt) {
        const float* xt = xb + tt * 128;
#pragma unroll
        for (int i = 0; i < 4; ++i) {
            const int p    = t + 256 * i;
            const int ch   = p >> 4;
            const int off8 = (p & 15) * 8;
            const float4 v0 = *(const float4*)(xt + (size_t)ch * HWSZ + off8);
            const float4 v1 = *(const float4*)(xt + (size_t)ch * HWSZ + off8 + 4);
            fsum[i] += (v0.x + v0.y) + (v0.z + v0.w) + (v1.x + v1.y) + (v1.z + v1.w);
            f16x8 hv;
            hv[0] = (f16)v0.x; hv[1] = (f16)v0.y; hv[2] = (f16)v0.z; hv[3] = (f16)v0.w;
            hv[4] = (f16)v1.x; hv[5] = (f16)v1.y; hv[6] = (f16)v1.z; hv[7] = (f16)v1.w;
            *(f16x8*)&tile[ch * 128 + (off8 ^ ((ch & 7) << 3))] = hv;
        }
        __syncthreads();

        f16x8 frag[4];
#pragma unroll
        for (int rb = 0; rb < 4; ++rb) {
            const int ch = rb * 16 + (l & 15);
            const int k0 = w * 32 + (l >> 4) * 8;
            frag[rb] = *(const f16x8*)&tile[ch * 128 + (k0 ^ ((ch & 7) << 3))];
        }
#pragma unroll
        for (int i = 0; i < 4; ++i)
#pragma unroll
            for (int j = 0; j < 4; ++j)
                acc[i][j] = MFMA16(frag[i], frag[j], acc[i][j]);
        __syncthreads();
    }

#pragma unroll
    for (int i = 0; i < 4; ++i) {
        fsum[i] += __shfl_xor(fsum[i], 1);
        fsum[i] += __shfl_xor(fsum[i], 2);
        fsum[i] += __shfl_xor(fsum[i], 4);
        fsum[i] += __shfl_xor(fsum[i], 8);
    }
    if ((l & 15) == 0) {
        const int chb = t >> 4;
#pragma unroll
        for (int i = 0; i < 4; ++i)
            spart[(size_t)bid * 64 + chb + 16 * i] = fsum[i];
    }

    // cross-wave accumulator reduce in 2 stages (32KB)
    if (w >= 2) {
#pragma unroll
        for (int i = 0; i < 4; ++i)
#pragma unroll
            for (int j = 0; j < 4; ++j)
#pragma unroll
                for (int r = 0; r < 4; ++r) {
                    const int row = i * 16 + (l >> 4) * 4 + r;
                    const int col = j * 16 + (l & 15);
                    red[w - 2][row * 64 + col] = acc[i][j][r];
                }
    }
    __syncthreads();
    if (w < 2) {
#pragma unroll
        for (int i = 0; i < 4; ++i)
#pragma unroll
            for (int j = 0; j < 4; ++j)
#pragma unroll
                for (int r = 0; r < 4; ++r) {
                    const int row = i * 16 + (l >> 4) * 4 + r;
                    const int col = j * 16 + (l & 15);
                    red[w][row * 64 + col] += acc[i][j][r];
                }
    }
    __syncthreads();
#pragma unroll
    for (int k = 0; k < 16; ++k) {
        const int e = t + 256 * k;
        gpart[(size_t)bid * 4096 + e] = red[0][e] + red[1][e];
    }
}

// ---------------------------------------------------------------------------
// Kernel 2: per-group inverse matrix sqrt (validated R10): fused partial
// reduction + [5/5] Pade + Neumann-4 solve P^{-1}Q (||E||~0.06 -> 8e-7 rel).
// ---------------------------------------------------------------------------
__global__ __launch_bounds__(256) void solve_k(const float* __restrict__ gpart,
                                               const float* __restrict__ spart,
                                               const float* __restrict__ wgt,
                                               const float* __restrict__ bias,
                                               f16* __restrict__ Tf,
                                               float* __restrict__ offv) {
    __shared__ __align__(16) float A[64 * P68];
    __shared__ __align__(16) float B[64 * P68];
    __shared__ __align__(16) float Cc[64 * P68];
    __shared__ __align__(16) float Dd[64 * P68];
    __shared__ float mus[64];
    __shared__ float red[4];
    __shared__ float tr16[16];

    const int g = blockIdx.x, t = threadIdx.x;

    float covv[16], cov2[16];
#pragma unroll
    for (int k = 0; k < 16; ++k) { covv[k] = 0.f; cov2[k] = 0.f; }
    for (int p = 0; p < 64; p += 2) {
        const float* gp0 = gpart + ((size_t)(g * 64 + p)) * 4096;
        const float* gp1 = gp0 + 4096;
#pragma unroll
        for (int k = 0; k < 16; ++k) {
            covv[k] += gp0[t + 256 * k];
            cov2[k] += gp1[t + 256 * k];
        }
    }
#pragma unroll
    for (int k = 0; k < 16; ++k) covv[k] += cov2[k];

    if (t < 64) {
        float ss = 0.f;
#pragma unroll 8
        for (int p = 0; p < 64; ++p) ss += spart[(size_t)(g * 64 + p) * 64 + t];
        mus[t] = ss * (1.0f / MTOT);
    }
    __syncthreads();

    float loc = 0.f;
#pragma unroll
    for (int k = 0; k < 16; ++k) {
        const int e = t + 256 * k;
        const int i = e >> 6, j = e & 63;
        const float cv = covv[k] * (1.0f / MTOT) - mus[i] * mus[j] + (i == j ? EPSC : 0.f);
        covv[k] = cv;
        loc += cv * cv;
    }
#pragma unroll
    for (int o = 32; o > 0; o >>= 1) loc += __shfl_down(loc, o);
    if ((t & 63) == 0) red[t >> 6] = loc;
    __syncthreads();
    const float normM = sqrtf(red[0] + red[1] + red[2] + red[3]);
    const float ninv  = 1.0f / normM;

#pragma unroll
    for (int k = 0; k < 16; ++k) {
        const int e = t + 256 * k;
        const int i = e >> 6, j = e & 63;
        const float pa = (i == j ? 1.f : 0.f) - covv[k] * ninv;
        A[i * P68 + j] = pa;
        B[i * P68 + j] = pa;
    }
    __syncthreads();

    const int ty = t >> 4, tx = t & 15;
    const int i0 = ty * 4, j0 = tx * 4;

    const float PP[6] = {1.f, -2.75f, 2.75f, -1.203125f, 0.21484375f, -0.0107421875f};
    const float QQ[6] = {1.f, -2.25f, 1.75f, -0.546875f, 0.05859375f, -0.0009765625f};

    float pacc[4][4], qacc[4][4];
#pragma unroll
    for (int ai = 0; ai < 4; ++ai)
#pragma unroll
        for (int bi = 0; bi < 4; ++bi) {
            const int i = i0 + ai, j = j0 + bi;
            const float pa = A[i * P68 + j];
            const float id = (i == j) ? 1.f : 0.f;
            pacc[ai][bi] = PP[0] * id + PP[1] * pa;
            qacc[ai][bi] = QQ[0] * id + QQ[1] * pa;
        }

    float* src = B;
    float* dst = Cc;
    for (int s = 0; s < 4; ++s) {
        float mm[4][4];
#pragma unroll
        for (int ai = 0; ai < 4; ++ai)
#pragma unroll
            for (int bi = 0; bi < 4; ++bi) mm[ai][bi] = 0.f;
        for (int kk = 0; kk < 64; ++kk) {
            const float4 a4 = *(const float4*)&src[kk * P68 + i0];
            const float4 b4 = *(const float4*)&A[kk * P68 + j0];
            const float av[4] = {a4.x, a4.y, a4.z, a4.w};
            const float bv[4] = {b4.x, b4.y, b4.z, b4.w};
#pragma unroll
            for (int ai = 0; ai < 4; ++ai)
#pragma unroll
                for (int bi = 0; bi < 4; ++bi)
                    mm[ai][bi] = fmaf(av[ai], bv[bi], mm[ai][bi]);
        }
#pragma unroll
        for (int ai = 0; ai < 4; ++ai) {
            float4 w4;
            w4.x = mm[ai][0]; w4.y = mm[ai][1]; w4.z = mm[ai][2]; w4.w = mm[ai][3];
            *(float4*)&dst[(i0 + ai) * P68 + j0] = w4;
        }
#pragma unroll
        for (int ai = 0; ai < 4; ++ai)
#pragma unroll
            for (int bi = 0; bi < 4; ++bi) {
                pacc[ai][bi] = fmaf(PP[s + 2], mm[ai][bi], pacc[ai][bi]);
                qacc[ai][bi] = fmaf(QQ[s + 2], mm[ai][bi], qacc[ai][bi]);
            }
        __syncthreads();
        float* tmpp = src; src = dst; dst = tmpp;
    }

    if (ty == tx)
        tr16[tx] = pacc[0][0] + pacc[1][1] + pacc[2][2] + pacc[3][3];
    __syncthreads();
    float trsum = 0.f;
#pragma unroll
    for (int i = 0; i < 16; ++i) trsum += tr16[i];
    const float cP  = trsum * (1.0f / 64.0f);
    const float icP = 1.0f / cP;

#pragma unroll
    for (int ai = 0; ai < 4; ++ai) {
        float4 we, wq;
        const int i = i0 + ai;
        we.x = pacc[ai][0] * icP - (i == j0 + 0 ? 1.f : 0.f);
        we.y = pacc[ai][1] * icP - (i == j0 + 1 ? 1.f : 0.f);
        we.z = pacc[ai][2] * icP - (i == j0 + 2 ? 1.f : 0.f);
        we.w = pacc[ai][3] * icP - (i == j0 + 3 ? 1.f : 0.f);
        wq.x = qacc[ai][0]; wq.y = qacc[ai][1]; wq.z = qacc[ai][2]; wq.w = qacc[ai][3];
        *(float4*)&A[i * P68 + j0] = we;
        *(float4*)&B[i * P68 + j0] = wq;
    }
    __syncthreads();

    float* rsrc = B;
    float* rdst = Cc;
    for (int it = 0; it < 4; ++it) {
        float mm[4][4];
#pragma unroll
        for (int ai = 0; ai < 4; ++ai)
#pragma unroll
            for (int bi = 0; bi < 4; ++bi) mm[ai][bi] = 0.f;
        for (int kk = 0; kk < 64; ++kk) {
            const float4 a4 = *(const float4*)&A[kk * P68 + i0];
            const float4 b4 = *(const float4*)&rsrc[kk * P68 + j0];
            const float av[4] = {a4.x, a4.y, a4.z, a4.w};
            const float bv[4] = {b4.x, b4.y, b4.z, b4.w};
#pragma unroll
            for (int ai = 0; ai < 4; ++ai)
#pragma unroll
                for (int bi = 0; bi < 4; ++bi)
                    mm[ai][bi] = fmaf(av[ai], bv[bi], mm[ai][bi]);
        }
#pragma unroll
        for (int ai = 0; ai < 4; ++ai) {
            const float4 q4 = *(const float4*)&B[(i0 + ai) * P68 + j0];
            float4 w4;
            w4.x = q4.x - mm[ai][0]; w4.y = q4.y - mm[ai][1];
            w4.z = q4.z - mm[ai][2]; w4.w = q4.w - mm[ai][3];
            *(float4*)&rdst[(i0 + ai) * P68 + j0] = w4;
        }
        __syncthreads();
        if (it == 0) { rsrc = Cc; rdst = Dd; }
        else { float* tmpp = rsrc; rsrc = rdst; rdst = tmpp; }
    }
    float* X = rsrc;

    const float invs = icP / sqrtf(normM);
    if (t < 64) {
        float sm = 0.f;
        for (int j = 0; j < 64; ++j) sm += X[t * P68 + j] * mus[j];
        offv[g * NM + t] = bias[g * NM + t] - sm * invs * wgt[g * NM + t];
    }
#pragma unroll
    for (int k = 0; k < 16; ++k) {
        const int e = t + 256 * k;
        const int i = e >> 6, j = e & 63;
        Tf[(size_t)g * 4096 + e] = (f16)(X[i * P68 + j] * invs * wgt[g * NM + i]);
    }
}

// ---------------------------------------------------------------------------
// Kernel 3: out = T @ x + off via f16 MFMA (R10 config) with REVERSED
// TILE order (tt = 15..0): reads each slice MRU-end first so the out-write
// eviction stream consumes the LRU end we reach last (anti-pursuit).
// ---------------------------------------------------------------------------
__global__ __launch_bounds__(256) void apply_k(const float* __restrict__ x,
                                               const f16* __restrict__ Tf,
                                               const float* __restrict__ offv,
                                               float* __restrict__ out) {
    __shared__ __align__(16) f16 xs[128 * 64];
    __shared__ __align__(16) f16 Ts[4096];
    __shared__ float offs[64];

    const int bid  = 511 - (int)blockIdx.x;
    const int g    = bid >> 6;
    const int n    = (bid >> 1) & 31;
    const int half = bid & 1;
    const size_t base = ((size_t)(n * CHAN + g * NM)) * HWSZ + half * 2048;
    const float* xb = x + base;
    float* ob = out + base;

    const int t = threadIdx.x;
    const int w = t >> 6;
    const int l = t & 63;

#pragma unroll
    for (int i = 0; i < 2; ++i) {
        const int c   = t + 256 * i;
        const int oc  = c >> 3;
        const int icb = (c & 7) * 8;
        const f16x8 v = *(const f16x8*)&Tf[(size_t)g * 4096 + oc * 64 + icb];
        *(f16x8*)&Ts[oc * 64 + (icb ^ ((oc & 7) << 3))] = v;
    }
    if (t < 64) offs[t] = offv[g * NM + t];
    __syncthreads();

    f16x8 afrag[2];
#pragma unroll
    for (int c = 0; c < 2; ++c) {
        const int oc = w * 16 + (l & 15);
        const int k0 = c * 32 + (l >> 4) * 8;
        afrag[c] = *(const f16x8*)&Ts[oc * 64 + (k0 ^ ((oc & 7) << 3))];
    }
    float offr[4];
#pragma unroll
    for (int r = 0; r < 4; ++r) offr[r] = offs[w * 16 + (l >> 4) * 4 + r];

    for (int tt = 15; tt >= 0; --tt) {
        const float* xt = xb + tt * 128;
        __syncthreads();
#pragma unroll
        for (int i = 0; i < 4; ++i) {
            const int p    = t + 256 * i;
            const int ch   = p >> 4;
            const int off8 = (p & 15) * 8;
            const float4 v0 = *(const float4*)(xt + (size_t)ch * HWSZ + off8);
            const float4 v1 = *(const float4*)(xt + (size_t)ch * HWSZ + off8 + 4);
            f16 h[8];
            h[0] = (f16)v0.x; h[1] = (f16)v0.y; h[2] = (f16)v0.z; h[3] = (f16)v0.w;
            h[4] = (f16)v1.x; h[5] = (f16)v1.y; h[6] = (f16)v1.z; h[7] = (f16)v1.w;
#pragma unroll
            for (int j = 0; j < 8; ++j) {
                const int pos = off8 + j;
                xs[pos * 64 + (ch ^ (((pos ^ (pos >> 3)) & 7) << 3))] = h[j];
            }
        }
        __syncthreads();

#pragma unroll
        for (int pb = 0; pb < 8; ++pb) {
            f32x4 acc;
            acc[0] = offr[0]; acc[1] = offr[1]; acc[2] = offr[2]; acc[3] = offr[3];
            const int pos = pb * 16 + (l & 15);
            const int swz = ((pos ^ (pos >> 3)) & 7) << 3;
#pragma unroll
            for (int c = 0; c < 2; ++c) {
                const int k0 = c * 32 + (l >> 4) * 8;
                const f16x8 bfrag = *(const f16x8*)&xs[pos * 64 + (k0 ^ swz)];
                acc = MFMA16(afrag[c], bfrag, acc);
            }
            const int posg = tt * 128 + pb * 16 + (l & 15);
#pragma unroll
            for (int r = 0; r < 4; ++r) {
                const int oc = w * 16 + (l >> 4) * 4 + r;
                ob[(size_t)oc * HWSZ + posg] = acc[r];
            }
        }
    }
}

// ---------------------------------------------------------------------------
extern "C" void kernel_launch(void* const* d_in, const int* in_sizes, int n_in,
                              void* d_out, int out_size, void* d_ws, size_t ws_size,
                              hipStream_t stream) {
    const float* x    = (const float*)d_in[0];
    const float* wgt  = (const float*)d_in[1];
    const float* bias = (const float*)d_in[2];
    float* out = (float*)d_out;

    float* ws    = (float*)d_ws;
    float* gpart = ws;                        // 512*4096 floats (8MB)
    float* spart = ws + 2097152;              // 512*64
    float* offv  = ws + 2129920;              // 512
    f16*   Tf    = (f16*)(ws + 2130432);      // 8*4096 halves

    gram_k <<<512, 256, 0, stream>>>(x, gpart, spart);
    solve_k<<<8,   256, 0, stream>>>(gpart, spart, wgt, bias, Tf, offv);
    apply_k<<<512, 256, 0, stream>>>(x, Tf, offv, out);
}

// Round 13
// 211.595 us; speedup vs baseline: 1.1988x; 1.0169x over previous
//
#include <hip/hip_runtime.h>

#define NBATCH 32
#define CHAN   512
#define HWSZ   4096
#define NG     8
#define NM     64
#define MTOT   (NBATCH * HWSZ)   // 131072 samples per channel
#define EPSC   0.01f
#define P68    68                // padded LDS row stride for solve matrices

typedef _Float16 f16;
typedef _Float16 f16x8 __attribute__((ext_vector_type(8)));
typedef float    f32x4 __attribute__((ext_vector_type(4)));

#define MFMA16(a, b, c) __builtin_amdgcn_mfma_f32_16x16x32_f16(a, b, c, 0, 0, 0)

// ---------------------------------------------------------------------------
// Kernel 1: per-block partial Gram via f16 MFMA + per-channel partial sums.
// R5/R10-validated LDS-staged version. LDS tile [64 ch][128 pos] f16,
// swizzle off8 ^= (ch&7)<<3; A-frag == B-frag for X X^T.
// ---------------------------------------------------------------------------
__global__ __launch_bounds__(256) void gram_k(const float* __restrict__ x,
                                              float* __restrict__ gpart,
                                              float* __restrict__ spart) {
    __shared__ __align__(16) f16 tile[64 * 128];
    __shared__ float red[2][4096];

    const int bid  = blockIdx.x;     // 0..511
    const int g    = bid >> 6;
    const int n    = (bid >> 1) & 31;
    const int half = bid & 1;
    const float* xb = x + ((size_t)(n * CHAN + g * NM)) * HWSZ + half * 2048;

    const int t = threadIdx.x;
    const int w = t >> 6;            // wave 0..3
    const int l = t & 63;

    f32x4 acc[4][4];
#pragma unroll
    for (int i = 0; i < 4; ++i)
#pragma unroll
        for (int j = 0; j < 4; ++j) acc[i][j] = (f32x4){0.f, 0.f, 0.f, 0.f};
    float fsum[4] = {0.f, 0.f, 0.f, 0.f};

    for (int tt = 0; tt < 16; ++tt) {
        const float* xt = xb + tt * 128;
#pragma unroll
        for (int i = 0; i < 4; ++i) {
            const int p    = t + 256 * i;
            const int ch   = p >> 4;
            const int off8 = (p & 15) * 8;
            const float4 v0 = *(const float4*)(xt + (size_t)ch * HWSZ + off8);
            const float4 v1 = *(const float4*)(xt + (size_t)ch * HWSZ + off8 + 4);
            fsum[i] += (v0.x + v0.y) + (v0.z + v0.w) + (v1.x + v1.y) + (v1.z + v1.w);
            f16x8 hv;
            hv[0] = (f16)v0.x; hv[1] = (f16)v0.y; hv[2] = (f16)v0.z; hv[3] = (f16)v0.w;
            hv[4] = (f16)v1.x; hv[5] = (f16)v1.y; hv[6] = (f16)v1.z; hv[7] = (f16)v1.w;
            *(f16x8*)&tile[ch * 128 + (off8 ^ ((ch & 7) << 3))] = hv;
        }
        __syncthreads();

        f16x8 frag[4];
#pragma unroll
        for (int rb = 0; rb < 4; ++rb) {
            const int ch = rb * 16 + (l & 15);
            const int k0 = w * 32 + (l >> 4) * 8;
            frag[rb] = *(const f16x8*)&tile[ch * 128 + (k0 ^ ((ch & 7) << 3))];
        }
#pragma unroll
        for (int i = 0; i < 4; ++i)
#pragma unroll
            for (int j = 0; j < 4; ++j)
                acc[i][j] = MFMA16(frag[i], frag[j], acc[i][j]);
        __syncthreads();
    }

#pragma unroll
    for (int i = 0; i < 4; ++i) {
        fsum[i] += __shfl_xor(fsum[i], 1);
        fsum[i] += __shfl_xor(fsum[i], 2);
        fsum[i] += __shfl_xor(fsum[i], 4);
        fsum[i] += __shfl_xor(fsum[i], 8);
    }
    if ((l & 15) == 0) {
        const int chb = t >> 4;
#pragma unroll
        for (int i = 0; i < 4; ++i)
            spart[(size_t)bid * 64 + chb + 16 * i] = fsum[i];
    }

    // cross-wave accumulator reduce in 2 stages (32KB)
    if (w >= 2) {
#pragma unroll
        for (int i = 0; i < 4; ++i)
#pragma unroll
            for (int j = 0; j < 4; ++j)
#pragma unroll
                for (int r = 0; r < 4; ++r) {
                    const int row = i * 16 + (l >> 4) * 4 + r;
                    const int col = j * 16 + (l & 15);
                    red[w - 2][row * 64 + col] = acc[i][j][r];
                }
    }
    __syncthreads();
    if (w < 2) {
#pragma unroll
        for (int i = 0; i < 4; ++i)
#pragma unroll
            for (int j = 0; j < 4; ++j)
#pragma unroll
                for (int r = 0; r < 4; ++r) {
                    const int row = i * 16 + (l >> 4) * 4 + r;
                    const int col = j * 16 + (l & 15);
                    red[w][row * 64 + col] += acc[i][j][r];
                }
    }
    __syncthreads();
#pragma unroll
    for (int k = 0; k < 16; ++k) {
        const int e = t + 256 * k;
        gpart[(size_t)bid * 4096 + e] = red[0][e] + red[1][e];
    }
}

// ---------------------------------------------------------------------------
// Kernel 2: per-group inverse matrix sqrt (validated R10): fused partial
// reduction + [5/5] Pade + Neumann-4 solve P^{-1}Q (||E||~0.06 -> 8e-7 rel).
// ---------------------------------------------------------------------------
__global__ __launch_bounds__(256) void solve_k(const float* __restrict__ gpart,
                                               const float* __restrict__ spart,
                                               const float* __restrict__ wgt,
                                               const float* __restrict__ bias,
                                               f16* __restrict__ Tf,
                                               float* __restrict__ offv) {
    __shared__ __align__(16) float A[64 * P68];
    __shared__ __align__(16) float B[64 * P68];
    __shared__ __align__(16) float Cc[64 * P68];
    __shared__ __align__(16) float Dd[64 * P68];
    __shared__ float mus[64];
    __shared__ float red[4];
    __shared__ float tr16[16];

    const int g = blockIdx.x, t = threadIdx.x;

    float covv[16], cov2[16];
#pragma unroll
    for (int k = 0; k < 16; ++k) { covv[k] = 0.f; cov2[k] = 0.f; }
    for (int p = 0; p < 64; p += 2) {
        const float* gp0 = gpart + ((size_t)(g * 64 + p)) * 4096;
        const float* gp1 = gp0 + 4096;
#pragma unroll
        for (int k = 0; k < 16; ++k) {
            covv[k] += gp0[t + 256 * k];
            cov2[k] += gp1[t + 256 * k];
        }
    }
#pragma unroll
    for (int k = 0; k < 16; ++k) covv[k] += cov2[k];

    if (t < 64) {
        float ss = 0.f;
#pragma unroll 8
        for (int p = 0; p < 64; ++p) ss += spart[(size_t)(g * 64 + p) * 64 + t];
        mus[t] = ss * (1.0f / MTOT);
    }
    __syncthreads();

    float loc = 0.f;
#pragma unroll
    for (int k = 0; k < 16; ++k) {
        const int e = t + 256 * k;
        const int i = e >> 6, j = e & 63;
        const float cv = covv[k] * (1.0f / MTOT) - mus[i] * mus[j] + (i == j ? EPSC : 0.f);
        covv[k] = cv;
        loc += cv * cv;
    }
#pragma unroll
    for (int o = 32; o > 0; o >>= 1) loc += __shfl_down(loc, o);
    if ((t & 63) == 0) red[t >> 6] = loc;
    __syncthreads();
    const float normM = sqrtf(red[0] + red[1] + red[2] + red[3]);
    const float ninv  = 1.0f / normM;

#pragma unroll
    for (int k = 0; k < 16; ++k) {
        const int e = t + 256 * k;
        const int i = e >> 6, j = e & 63;
        const float pa = (i == j ? 1.f : 0.f) - covv[k] * ninv;
        A[i * P68 + j] = pa;
        B[i * P68 + j] = pa;
    }
    __syncthreads();

    const int ty = t >> 4, tx = t & 15;
    const int i0 = ty * 4, j0 = tx * 4;

    const float PP[6] = {1.f, -2.75f, 2.75f, -1.203125f, 0.21484375f, -0.0107421875f};
    const float QQ[6] = {1.f, -2.25f, 1.75f, -0.546875f, 0.05859375f, -0.0009765625f};

    float pacc[4][4], qacc[4][4];
#pragma unroll
    for (int ai = 0; ai < 4; ++ai)
#pragma unroll
        for (int bi = 0; bi < 4; ++bi) {
            const int i = i0 + ai, j = j0 + bi;
            const float pa = A[i * P68 + j];
            const float id = (i == j) ? 1.f : 0.f;
            pacc[ai][bi] = PP[0] * id + PP[1] * pa;
            qacc[ai][bi] = QQ[0] * id + QQ[1] * pa;
        }

    float* src = B;
    float* dst = Cc;
    for (int s = 0; s < 4; ++s) {
        float mm[4][4];
#pragma unroll
        for (int ai = 0; ai < 4; ++ai)
#pragma unroll
            for (int bi = 0; bi < 4; ++bi) mm[ai][bi] = 0.f;
        for (int kk = 0; kk < 64; ++kk) {
            const float4 a4 = *(const float4*)&src[kk * P68 + i0];
            const float4 b4 = *(const float4*)&A[kk * P68 + j0];
            const float av[4] = {a4.x, a4.y, a4.z, a4.w};
            const float bv[4] = {b4.x, b4.y, b4.z, b4.w};
#pragma unroll
            for (int ai = 0; ai < 4; ++ai)
#pragma unroll
                for (int bi = 0; bi < 4; ++bi)
                    mm[ai][bi] = fmaf(av[ai], bv[bi], mm[ai][bi]);
        }
#pragma unroll
        for (int ai = 0; ai < 4; ++ai) {
            float4 w4;
            w4.x = mm[ai][0]; w4.y = mm[ai][1]; w4.z = mm[ai][2]; w4.w = mm[ai][3];
            *(float4*)&dst[(i0 + ai) * P68 + j0] = w4;
        }
#pragma unroll
        for (int ai = 0; ai < 4; ++ai)
#pragma unroll
            for (int bi = 0; bi < 4; ++bi) {
                pacc[ai][bi] = fmaf(PP[s + 2], mm[ai][bi], pacc[ai][bi]);
                qacc[ai][bi] = fmaf(QQ[s + 2], mm[ai][bi], qacc[ai][bi]);
            }
        __syncthreads();
        float* tmpp = src; src = dst; dst = tmpp;
    }

    if (ty == tx)
        tr16[tx] = pacc[0][0] + pacc[1][1] + pacc[2][2] + pacc[3][3];
    __syncthreads();
    float trsum = 0.f;
#pragma unroll
    for (int i = 0; i < 16; ++i) trsum += tr16[i];
    const float cP  = trsum * (1.0f / 64.0f);
    const float icP = 1.0f / cP;

#pragma unroll
    for (int ai = 0; ai < 4; ++ai) {
        float4 we, wq;
        const int i = i0 + ai;
        we.x = pacc[ai][0] * icP - (i == j0 + 0 ? 1.f : 0.f);
        we.y = pacc[ai][1] * icP - (i == j0 + 1 ? 1.f : 0.f);
        we.z = pacc[ai][2] * icP - (i == j0 + 2 ? 1.f : 0.f);
        we.w = pacc[ai][3] * icP - (i == j0 + 3 ? 1.f : 0.f);
        wq.x = qacc[ai][0]; wq.y = qacc[ai][1]; wq.z = qacc[ai][2]; wq.w = qacc[ai][3];
        *(float4*)&A[i * P68 + j0] = we;
        *(float4*)&B[i * P68 + j0] = wq;
    }
    __syncthreads();

    float* rsrc = B;
    float* rdst = Cc;
    for (int it = 0; it < 4; ++it) {
        float mm[4][4];
#pragma unroll
        for (int ai = 0; ai < 4; ++ai)
#pragma unroll
            for (int bi = 0; bi < 4; ++bi) mm[ai][bi] = 0.f;
        for (int kk = 0; kk < 64; ++kk) {
            const float4 a4 = *(const float4*)&A[kk * P68 + i0];
            const float4 b4 = *(const float4*)&rsrc[kk * P68 + j0];
            const float av[4] = {a4.x, a4.y, a4.z, a4.w};
            const float bv[4] = {b4.x, b4.y, b4.z, b4.w};
#pragma unroll
            for (int ai = 0; ai < 4; ++ai)
#pragma unroll
                for (int bi = 0; bi < 4; ++bi)
                    mm[ai][bi] = fmaf(av[ai], bv[bi], mm[ai][bi]);
        }
#pragma unroll
        for (int ai = 0; ai < 4; ++ai) {
            const float4 q4 = *(const float4*)&B[(i0 + ai) * P68 + j0];
            float4 w4;
            w4.x = q4.x - mm[ai][0]; w4.y = q4.y - mm[ai][1];
            w4.z = q4.z - mm[ai][2]; w4.w = q4.w - mm[ai][3];
            *(float4*)&rdst[(i0 + ai) * P68 + j0] = w4;
        }
        __syncthreads();
        if (it == 0) { rsrc = Cc; rdst = Dd; }
        else { float* tmpp = rsrc; rsrc = rdst; rdst = tmpp; }
    }
    float* X = rsrc;

    const float invs = icP / sqrtf(normM);
    if (t < 64) {
        float sm = 0.f;
        for (int j = 0; j < 64; ++j) sm += X[t * P68 + j] * mus[j];
        offv[g * NM + t] = bias[g * NM + t] - sm * invs * wgt[g * NM + t];
    }
#pragma unroll
    for (int k = 0; k < 16; ++k) {
        const int e = t + 256 * k;
        const int i = e >> 6, j = e & 63;
        Tf[(size_t)g * 4096 + e] = (f16)(X[i * P68 + j] * invs * wgt[g * NM + i]);
    }
}

// ---------------------------------------------------------------------------
// Kernel 3: out = T @ x + off via f16 MFMA (R12 config: reversed tile order,
// anti-pursuit) + NONTEMPORAL out stores: out is never re-read, so nt stops
// the 268MB write stream from evicting x's L3 residency.
// ---------------------------------------------------------------------------
__global__ __launch_bounds__(256) void apply_k(const float* __restrict__ x,
                                               const f16* __restrict__ Tf,
                                               const float* __restrict__ offv,
                                               float* __restrict__ out) {
    __shared__ __align__(16) f16 xs[128 * 64];
    __shared__ __align__(16) f16 Ts[4096];
    __shared__ float offs[64];

    const int bid  = 511 - (int)blockIdx.x;
    const int g    = bid >> 6;
    const int n    = (bid >> 1) & 31;
    const int half = bid & 1;
    const size_t base = ((size_t)(n * CHAN + g * NM)) * HWSZ + half * 2048;
    const float* xb = x + base;
    float* ob = out + base;

    const int t = threadIdx.x;
    const int w = t >> 6;
    const int l = t & 63;

#pragma unroll
    for (int i = 0; i < 2; ++i) {
        const int c   = t + 256 * i;
        const int oc  = c >> 3;
        const int icb = (c & 7) * 8;
        const f16x8 v = *(const f16x8*)&Tf[(size_t)g * 4096 + oc * 64 + icb];
        *(f16x8*)&Ts[oc * 64 + (icb ^ ((oc & 7) << 3))] = v;
    }
    if (t < 64) offs[t] = offv[g * NM + t];
    __syncthreads();

    f16x8 afrag[2];
#pragma unroll
    for (int c = 0; c < 2; ++c) {
        const int oc = w * 16 + (l & 15);
        const int k0 = c * 32 + (l >> 4) * 8;
        afrag[c] = *(const f16x8*)&Ts[oc * 64 + (k0 ^ ((oc & 7) << 3))];
    }
    float offr[4];
#pragma unroll
    for (int r = 0; r < 4; ++r) offr[r] = offs[w * 16 + (l >> 4) * 4 + r];

    for (int tt = 15; tt >= 0; --tt) {
        const float* xt = xb + tt * 128;
        __syncthreads();
#pragma unroll
        for (int i = 0; i < 4; ++i) {
            const int p    = t + 256 * i;
            const int ch   = p >> 4;
            const int off8 = (p & 15) * 8;
            const float4 v0 = *(const float4*)(xt + (size_t)ch * HWSZ + off8);
            const float4 v1 = *(const float4*)(xt + (size_t)ch * HWSZ + off8 + 4);
            f16 h[8];
            h[0] = (f16)v0.x; h[1] = (f16)v0.y; h[2] = (f16)v0.z; h[3] = (f16)v0.w;
            h[4] = (f16)v1.x; h[5] = (f16)v1.y; h[6] = (f16)v1.z; h[7] = (f16)v1.w;
#pragma unroll
            for (int j = 0; j < 8; ++j) {
                const int pos = off8 + j;
                xs[pos * 64 + (ch ^ (((pos ^ (pos >> 3)) & 7) << 3))] = h[j];
            }
        }
        __syncthreads();

#pragma unroll
        for (int pb = 0; pb < 8; ++pb) {
            f32x4 acc;
            acc[0] = offr[0]; acc[1] = offr[1]; acc[2] = offr[2]; acc[3] = offr[3];
            const int pos = pb * 16 + (l & 15);
            const int swz = ((pos ^ (pos >> 3)) & 7) << 3;
#pragma unroll
            for (int c = 0; c < 2; ++c) {
                const int k0 = c * 32 + (l >> 4) * 8;
                const f16x8 bfrag = *(const f16x8*)&xs[pos * 64 + (k0 ^ swz)];
                acc = MFMA16(afrag[c], bfrag, acc);
            }
            const int posg = tt * 128 + pb * 16 + (l & 15);
#pragma unroll
            for (int r = 0; r < 4; ++r) {
                const int oc = w * 16 + (l >> 4) * 4 + r;
                __builtin_nontemporal_store(acc[r], &ob[(size_t)oc * HWSZ + posg]);
            }
        }
    }
}

// ---------------------------------------------------------------------------
extern "C" void kernel_launch(void* const* d_in, const int* in_sizes, int n_in,
                              void* d_out, int out_size, void* d_ws, size_t ws_size,
                              hipStream_t stream) {
    const float* x    = (const float*)d_in[0];
    const float* wgt  = (const float*)d_in[1];
    const float* bias = (const float*)d_in[2];
    float* out = (float*)d_out;

    float* ws    = (float*)d_ws;
    float* gpart = ws;                        // 512*4096 floats (8MB)
    float* spart = ws + 2097152;              // 512*64
    float* offv  = ws + 2129920;              // 512
    f16*   Tf    = (f16*)(ws + 2130432);      // 8*4096 halves

    gram_k <<<512, 256, 0, stream>>>(x, gpart, spart);
    solve_k<<<8,   256, 0, stream>>>(gpart, spart, wgt, bias, Tf, offv);
    apply_k<<<512, 256, 0, stream>>>(x, Tf, offv, out);
}